// Round 3
// baseline (41663.007 us; speedup 1.0000x reference)
//
#include <hip/hip_runtime.h>
#include <hip/hip_fp16.h>

typedef __attribute__((ext_vector_type(2))) _Float16 half2v;
typedef __attribute__((ext_vector_type(2))) __fp16   fp16x2;

#define SEQ     512
#define THREADS 512

// ws layout (uint4 units for weights):
#define WQ_OFF   0
#define WX_OFF   (64*512)
#define WH_OFF   (64*512 + 64*1536)
#define SYNC_OFF 3670016   // bytes: end of packed weights (229376*16)
// within sync region (bytes):
//   flag1 u32[256] @0 ; flag2 u32[256] @1024
//   Hbuf  u32[2][64][256] @2048      (131072 B)  h packed f16 pairs, double-buffered
//   Pbuf  f32[2][8][32][24] @133120  (49152 B)   partial scores
//   pooled f32[64][512] @182272
//   fc1    f32[64][512] @313344

__device__ inline unsigned int pack2f16(float a, float b) {
    fp16x2 p = __builtin_amdgcn_cvt_pkrtz(a, b);
    return __builtin_bit_cast(unsigned int, p);
}
__device__ inline float fdot2u(unsigned int a, unsigned int b, float acc) {
    return __builtin_amdgcn_fdot2(__builtin_bit_cast(half2v, a),
                                  __builtin_bit_cast(half2v, b), acc, false);
}
__device__ inline float dot4(uint4 h, uint4 w, float acc) {
    acc = fdot2u(h.x, w.x, acc); acc = fdot2u(h.y, w.y, acc);
    acc = fdot2u(h.z, w.z, acc); acc = fdot2u(h.w, w.w, acc);
    return acc;
}
__device__ inline float fsigmoid(float x) { return 1.f / (1.f + __expf(-x)); }
__device__ inline float ftanhf(float x) {
    float e = __expf(-2.f * fabsf(x));
    float t = (1.f - e) / (1.f + e);
    return copysignf(t, x);
}

__global__ __launch_bounds__(256)
void pack_weights(const float* __restrict__ Wq,
                  const float* __restrict__ Wx,
                  const float* __restrict__ Wh,
                  uint4* __restrict__ ws) {
    int tid = blockIdx.x * blockDim.x + threadIdx.x;  // 0 .. 229375
    const float* src; uint4* dst; int C, idx;
    if (tid < 64 * 512)                  { src = Wq; dst = ws;              C = 512;  idx = tid; }
    else if (tid < 64 * 512 + 64 * 1536) { src = Wx; dst = ws + WX_OFF;     C = 1536; idx = tid - 64 * 512; }
    else                                 { src = Wh; dst = ws + WH_OFF;     C = 1536; idx = tid - (64 * 512 + 64 * 1536); }
    int m4 = idx / C;
    int c  = idx - m4 * C;
    const float* s = src + (size_t)(m4 * 8) * C + c;
    uint4 o;
    o.x = pack2f16(s[0 * (size_t)C], s[1 * (size_t)C]);
    o.y = pack2f16(s[2 * (size_t)C], s[3 * (size_t)C]);
    o.z = pack2f16(s[4 * (size_t)C], s[5 * (size_t)C]);
    o.w = pack2f16(s[6 * (size_t)C], s[7 * (size_t)C]);
    dst[idx] = o;
}

// 256 blocks = 8 groups x 32 blocks. Group g owns batches 8g..8g+7.
// Block (bid in group) owns h-cols [bid*16, bid*16+16) and q-dims same range.
// Weight slices persistent in LDS; h / partial-scores exchanged via global + flags.
__global__ __launch_bounds__(THREADS)
void gru_scan(const int* __restrict__ xtok, const float* __restrict__ emb,
              const uint4* __restrict__ wsp, const float* __restrict__ bx,
              const float* __restrict__ bh, const float* __restrict__ W1,
              const float* __restrict__ b1, const float* __restrict__ W2,
              const float* __restrict__ b2, float* __restrict__ out)
{
    const int blk  = blockIdx.x;
    const int gid  = blk >> 5;
    const int bid  = blk & 31;
    const int tid  = threadIdx.x;
    const int lane = tid & 63;
    const int wid  = tid >> 6;          // ks for GEMMs
    const int colsub = lane & 7;
    const int bp     = (lane >> 3) & 3;
    const int chsub  = lane >> 5;

    char* sync = (char*)wsp + SYNC_OFF;
    unsigned int* flag1 = (unsigned int*)sync;
    unsigned int* flag2 = (unsigned int*)(sync + 1024);
    unsigned int* Hbuf  = (unsigned int*)(sync + 2048);
    float* Pbuf         = (float*)(sync + 133120);
    float* pooled_g     = (float*)(sync + 182272);
    float* fc1_g        = (float*)(sync + 313344);

    __shared__ uint4 lds_W [64][65];   // cols 0..15 = Wq-slice, 16..63 = Wh-slice (r,z,n x16)
    __shared__ uint4 lds_Wx[64][49];   // 48 Wx cols (r,z,n x16)
    __shared__ uint4 lds_h [8][66];
    __shared__ uint4 lds_ctx[8][66];
    __shared__ float red[8][64][9];
    __shared__ float sum[64][9];
    __shared__ float a_lds[8][8][3];
    __shared__ int   lds_tok[8][3];

    // ---- load persistent weight slices into LDS (once) ----
    for (int i = tid; i < 64 * 64; i += THREADS) {
        int ch = i >> 6, cl = i & 63;
        uint4 v;
        if (cl < 16) v = wsp[WQ_OFF + ch * 512 + bid * 16 + cl];
        else { int g = (cl - 16) >> 4, c = (cl - 16) & 15;
               v = wsp[WH_OFF + ch * 1536 + g * 512 + bid * 16 + c]; }
        lds_W[ch][cl] = v;
    }
    for (int i = tid; i < 64 * 48; i += THREADS) {
        int ch = i / 48, cl = i - ch * 48;
        int g = cl >> 4, c = cl & 15;
        lds_Wx[ch][cl] = wsp[WX_OFF + ch * 1536 + g * 512 + bid * 16 + c];
    }

    float bxr = 0, bxz = 0, bxn = 0, bhr = 0, bhz = 0, bhn = 0;
    if (tid < 128) {
        int c = tid >> 3;
        int cg = bid * 16 + c;
        bxr = bx[cg]; bxz = bx[512 + cg]; bxn = bx[1024 + cg];
        bhr = bh[cg]; bhz = bh[512 + cg]; bhn = bh[1024 + cg];
    }
    float hprev = 0.f, pooledv = 0.f;
    __syncthreads();

    for (int t = 0; t < SEQ; ++t) {
        const int par = t & 1;

        // ---- wait: h(t-1) published by all 32 blocks of this group ----
        if (wid == 0) {
            bool done = lane >= 32;
            while (!__all(done))
                if (!done) done = (__hip_atomic_load(&flag2[gid * 32 + lane],
                                   __ATOMIC_RELAXED, __HIP_MEMORY_SCOPE_AGENT) >= (unsigned)t);
            __threadfence();
        }
        __syncthreads();

        // tokens + score-window slice preload (wave 0)
        float winv[16];
        int b3 = 0, g3 = 0, trow = -1;
        if (tid < 24) {
            b3 = tid / 3; g3 = tid - b3 * 3;
            trow = t - 2 + g3;
            int tok = (trow >= 0) ? xtok[(gid * 8 + b3) * SEQ + trow] : -1;
            lds_tok[b3][g3] = tok;
            if (tok >= 0) {
                const float* er = emb + (size_t)tok * 512 + bid * 16;
                #pragma unroll
                for (int d = 0; d < 16; ++d) winv[d] = er[d];
            } else {
                #pragma unroll
                for (int d = 0; d < 16; ++d) winv[d] = 0.f;
            }
        }

        // ---- load full h(t-1) (f16-packed) into LDS ----
        {
            const uint4* hsrc = (const uint4*)(Hbuf + (size_t)(par ^ 1) * 16384);
            for (int i = tid; i < 8 * 64; i += THREADS) {
                int b = i >> 6, ch = i & 63;
                lds_h[b][ch] = hsrc[(gid * 8 + b) * 64 + ch];
            }
        }
        __syncthreads();

        // ---- GEMM1: [q(16) | gh(48)] = h @ [Wq|Wh] slice ----
        float acc[16];
        #pragma unroll
        for (int i = 0; i < 16; ++i) acc[i] = 0.f;
        {
            int ch0 = wid * 8 + chsub * 4;
            #pragma unroll
            for (int i = 0; i < 4; ++i) {
                int ch = ch0 + i;
                uint4 h0 = lds_h[bp][ch];
                uint4 h1 = lds_h[bp + 4][ch];
                #pragma unroll
                for (int j = 0; j < 8; ++j) {
                    uint4 w = lds_W[ch][colsub + 8 * j];
                    acc[j]     = dot4(h0, w, acc[j]);
                    acc[8 + j] = dot4(h1, w, acc[8 + j]);
                }
            }
        }
        #pragma unroll
        for (int i = 0; i < 16; ++i) acc[i] += __shfl_xor(acc[i], 32);
        if (chsub == 0) {
            #pragma unroll
            for (int j = 0; j < 8; ++j) {
                red[wid][colsub + 8 * j][bp]     = acc[j];
                red[wid][colsub + 8 * j][bp + 4] = acc[8 + j];
            }
        }
        __syncthreads();
        {
            int col = tid >> 3, b = tid & 7;
            float s = 0.f;
            #pragma unroll
            for (int k = 0; k < 8; ++k) s += red[k][col][b];
            sum[col][b] = s;
        }
        __syncthreads();

        // ---- partial attention scores -> Pbuf, publish flag1 ----
        if (tid < 24) {
            float s = 0.f;
            if (trow >= 0) {
                #pragma unroll
                for (int d = 0; d < 16; ++d) s += winv[d] * sum[d][b3];
            }
            Pbuf[(size_t)((par * 8 + gid) * 32 + bid) * 24 + b3 * 3 + g3] = s;
        }
        __threadfence();
        if (tid == 0)
            __hip_atomic_store(&flag1[gid * 32 + bid], (unsigned)(t + 1),
                               __ATOMIC_RELEASE, __HIP_MEMORY_SCOPE_AGENT);

        // ---- wait: all partial scores ----
        if (wid == 0) {
            bool done = lane >= 32;
            while (!__all(done))
                if (!done) done = (__hip_atomic_load(&flag1[gid * 32 + lane],
                                   __ATOMIC_RELAXED, __HIP_MEMORY_SCOPE_AGENT) >= (unsigned)(t + 1));
            __threadfence();
        }
        __syncthreads();

        // ---- softmax -> a (redundant per block, tiny) ----
        if (tid < 64) {
            int b = tid >> 3, n = tid & 7;
            const float* pb = Pbuf + (size_t)(par * 8 + gid) * 32 * 24;
            float sc0 = 0, sc1 = 0, sc2 = 0;
            #pragma unroll
            for (int j = 0; j < 4; ++j) {
                const float* pj = pb + (n * 4 + j) * 24 + b * 3;
                sc0 += pj[0]; sc1 += pj[1]; sc2 += pj[2];
            }
            sc0 *= 0.125f; sc1 *= 0.125f; sc2 *= 0.125f;
            float mx = fmaxf(sc0, fmaxf(sc1, sc2));
            float e0 = __expf(sc0 - mx), e1 = __expf(sc1 - mx), e2 = __expf(sc2 - mx);
            float inv = 1.f / (e0 + e1 + e2);
            a_lds[b][n][0] = e0 * inv; a_lds[b][n][1] = e1 * inv; a_lds[b][n][2] = e2 * inv;
        }
        __syncthreads();

        // ---- build ctx (full 512 dims, f16-packed) from window + a ----
        {
            int b = wid;
            int head = lane >> 3;
            float a0 = a_lds[b][head][0], a1 = a_lds[b][head][1], a2 = a_lds[b][head][2];
            int t0 = lds_tok[b][0], t1 = lds_tok[b][1], t2 = lds_tok[b][2];
            float c[8];
            #pragma unroll
            for (int e = 0; e < 8; ++e) c[e] = 0.f;
            if (t0 >= 0) {
                const float4* p = (const float4*)(emb + (size_t)t0 * 512 + lane * 8);
                float4 v0 = p[0], v1 = p[1];
                c[0] += a0 * v0.x; c[1] += a0 * v0.y; c[2] += a0 * v0.z; c[3] += a0 * v0.w;
                c[4] += a0 * v1.x; c[5] += a0 * v1.y; c[6] += a0 * v1.z; c[7] += a0 * v1.w;
            }
            if (t1 >= 0) {
                const float4* p = (const float4*)(emb + (size_t)t1 * 512 + lane * 8);
                float4 v0 = p[0], v1 = p[1];
                c[0] += a1 * v0.x; c[1] += a1 * v0.y; c[2] += a1 * v0.z; c[3] += a1 * v0.w;
                c[4] += a1 * v1.x; c[5] += a1 * v1.y; c[6] += a1 * v1.z; c[7] += a1 * v1.w;
            }
            if (t2 >= 0) {
                const float4* p = (const float4*)(emb + (size_t)t2 * 512 + lane * 8);
                float4 v0 = p[0], v1 = p[1];
                c[0] += a2 * v0.x; c[1] += a2 * v0.y; c[2] += a2 * v0.z; c[3] += a2 * v0.w;
                c[4] += a2 * v1.x; c[5] += a2 * v1.y; c[6] += a2 * v1.z; c[7] += a2 * v1.w;
            }
            uint4 pk;
            pk.x = pack2f16(c[0], c[1]); pk.y = pack2f16(c[2], c[3]);
            pk.z = pack2f16(c[4], c[5]); pk.w = pack2f16(c[6], c[7]);
            lds_ctx[b][lane] = pk;
        }
        __syncthreads();

        // ---- GEMM2: gx(48) = ctx @ Wx slice ----
        float acx[12];
        #pragma unroll
        for (int i = 0; i < 12; ++i) acx[i] = 0.f;
        {
            int ch0 = wid * 8 + chsub * 4;
            #pragma unroll
            for (int i = 0; i < 4; ++i) {
                int ch = ch0 + i;
                uint4 c0 = lds_ctx[bp][ch];
                uint4 c1 = lds_ctx[bp + 4][ch];
                #pragma unroll
                for (int j = 0; j < 6; ++j) {
                    uint4 w = lds_Wx[ch][colsub + 8 * j];
                    acx[j]     = dot4(c0, w, acx[j]);
                    acx[6 + j] = dot4(c1, w, acx[6 + j]);
                }
            }
        }
        #pragma unroll
        for (int i = 0; i < 12; ++i) acx[i] += __shfl_xor(acx[i], 32);
        if (chsub == 0) {
            #pragma unroll
            for (int j = 0; j < 6; ++j) {
                red[wid][colsub + 8 * j][bp]     = acx[j];
                red[wid][colsub + 8 * j][bp + 4] = acx[6 + j];
            }
        }
        __syncthreads();

        // ---- GRU pointwise + h publish (threads 0..127: c=tid>>3, b=tid&7) ----
        if (tid < 128) {
            int c = tid >> 3, b = tid & 7;
            float gxr = bxr, gxz = bxz, gxn = bxn;
            #pragma unroll
            for (int k = 0; k < 8; ++k) {
                gxr += red[k][c][b];
                gxz += red[k][16 + c][b];
                gxn += red[k][32 + c][b];
            }
            float ghr = sum[16 + c][b] + bhr;
            float ghz = sum[32 + c][b] + bhz;
            float ghn = sum[48 + c][b] + bhn;
            float r = fsigmoid(gxr + ghr);
            float z = fsigmoid(gxz + ghz);
            float n = ftanhf(gxn + r * ghn);
            float hnew = (1.f - z) * n + z * hprev;
            hprev = hnew; pooledv += hnew;
            float hnext = __shfl_down(hnew, 8);
            if ((c & 1) == 0)
                Hbuf[(size_t)par * 16384 + (gid * 8 + b) * 256 + bid * 8 + (c >> 1)]
                    = pack2f16(hnew, hnext);
        }
        __threadfence();
        __syncthreads();
        if (tid == 0)
            __hip_atomic_store(&flag2[gid * 32 + bid], (unsigned)(t + 1),
                               __ATOMIC_RELEASE, __HIP_MEMORY_SCOPE_AGENT);
    }

    // ---- epilogue: pooled -> relu -> FC1 -> FC2 ----
    if (tid < 128) {
        int c = tid >> 3, b = tid & 7;
        pooled_g[(gid * 8 + b) * 512 + bid * 16 + c] = fmaxf(pooledv, 0.f);
    }
    __threadfence();
    __syncthreads();
    if (tid == 0)
        __hip_atomic_store(&flag1[gid * 32 + bid], (unsigned)(SEQ + 1),
                           __ATOMIC_RELEASE, __HIP_MEMORY_SCOPE_AGENT);
    if (wid == 0) {
        bool done = lane >= 32;
        while (!__all(done))
            if (!done) done = (__hip_atomic_load(&flag1[gid * 32 + lane],
                               __ATOMIC_RELAXED, __HIP_MEMORY_SCOPE_AGENT) >= (unsigned)(SEQ + 1));
        __threadfence();
    }
    __syncthreads();

    if (tid < 128) {
        int c = tid >> 3, b = tid & 7;
        int cg = bid * 16 + c;
        const float* pr = pooled_g + (size_t)(gid * 8 + b) * 512;
        float acc1 = b1[cg];
        for (int k = 0; k < 512; ++k) acc1 += pr[k] * W1[(size_t)k * 512 + cg];
        fc1_g[(gid * 8 + b) * 512 + cg] = acc1;
    }
    __threadfence();
    __syncthreads();
    if (tid == 0)
        __hip_atomic_store(&flag2[gid * 32 + bid], (unsigned)(SEQ + 1),
                           __ATOMIC_RELEASE, __HIP_MEMORY_SCOPE_AGENT);

    if (bid == 0) {
        if (wid == 0) {
            bool done = lane >= 32;
            while (!__all(done))
                if (!done) done = (__hip_atomic_load(&flag2[gid * 32 + lane],
                                   __ATOMIC_RELAXED, __HIP_MEMORY_SCOPE_AGENT) >= (unsigned)(SEQ + 1));
            __threadfence();
        }
        __syncthreads();
        if (tid < 80) {
            int b = tid / 10, cls = tid - b * 10;
            const float* fr = fc1_g + (size_t)(gid * 8 + b) * 512;
            float a2 = b2[cls];
            for (int k = 0; k < 512; ++k) a2 += fr[k] * W2[k * 10 + cls];
            out[(gid * 8 + b) * 10 + cls] = a2;
        }
    }
}

extern "C" void kernel_launch(void* const* d_in, const int* in_sizes, int n_in,
                              void* d_out, int out_size, void* d_ws, size_t ws_size,
                              hipStream_t stream) {
    const int*   x   = (const int*)d_in[0];
    const float* emb = (const float*)d_in[1];
    const float* Wq  = (const float*)d_in[2];
    const float* Wx  = (const float*)d_in[3];
    const float* Wh  = (const float*)d_in[4];
    const float* bx  = (const float*)d_in[5];
    const float* bh  = (const float*)d_in[6];
    const float* W1  = (const float*)d_in[7];
    const float* b1  = (const float*)d_in[8];
    const float* W2  = (const float*)d_in[9];
    const float* b2  = (const float*)d_in[10];
    uint4* wsp = (uint4*)d_ws;
    float* outp = (float*)d_out;

    hipLaunchKernelGGL(pack_weights, dim3(896), dim3(256), 0, stream, Wq, Wx, Wh, wsp);
    hipMemsetAsync((char*)d_ws + SYNC_OFF, 0, 133120, stream);

    void* args[] = { (void*)&x, (void*)&emb, (void*)&wsp, (void*)&bx, (void*)&bh,
                     (void*)&W1, (void*)&b1, (void*)&W2, (void*)&b2, (void*)&outp };
    hipError_t e = hipLaunchCooperativeKernel((void*)gru_scan, dim3(256), dim3(THREADS),
                                              args, 0, stream);
    if (e != hipSuccess) {
        // fallback: plain launch (256 blocks, 1/CU by LDS -> co-resident in practice)
        hipLaunchKernelGGL(gru_scan, dim3(256), dim3(THREADS), 0, stream,
                           x, emb, wsp, bx, bh, W1, b1, W2, b2, outp);
    }
}

// Round 4
// 28451.703 us; speedup vs baseline: 1.4643x; 1.4643x over previous
//
#include <hip/hip_runtime.h>
#include <hip/hip_fp16.h>

typedef __attribute__((ext_vector_type(2))) _Float16 half2v;
typedef __attribute__((ext_vector_type(2))) __fp16   fp16x2;

#define SEQ     512
#define THREADS 512

// ws layout (uint4 units for weights):
#define WQ_OFF   0
#define WX_OFF   (64*512)
#define WH_OFF   (64*512 + 64*1536)
#define SYNC_OFF 3670016   // bytes: end of packed weights (229376*16)
// sync region (bytes): flagS u32[256]@0 ; flagH u32[256]@1024 ;
// Hbuf u32[2][8g][8b][256]@2048 (131072) ; Pbuf f32[2][8][32][24]@133120 ;
// pooled f32[64][512]@182272 ; fc1 f32[64][512]@313344

__device__ inline unsigned int pack2f16(float a, float b) {
    fp16x2 p = __builtin_amdgcn_cvt_pkrtz(a, b);
    return __builtin_bit_cast(unsigned int, p);
}
__device__ inline float fdot2u(unsigned int a, unsigned int b, float acc) {
    return __builtin_amdgcn_fdot2(__builtin_bit_cast(half2v, a),
                                  __builtin_bit_cast(half2v, b), acc, false);
}
__device__ inline float dot4(uint4 h, uint4 w, float acc) {
    acc = fdot2u(h.x, w.x, acc); acc = fdot2u(h.y, w.y, acc);
    acc = fdot2u(h.z, w.z, acc); acc = fdot2u(h.w, w.w, acc);
    return acc;
}
__device__ inline float fsigmoid(float x) { return 1.f / (1.f + __expf(-x)); }
__device__ inline float ftanhf(float x) {
    float e = __expf(-2.f * fabsf(x));
    float t = (1.f - e) / (1.f + e);
    return copysignf(t, x);
}

__global__ __launch_bounds__(256)
void pack_weights(const float* __restrict__ Wq,
                  const float* __restrict__ Wx,
                  const float* __restrict__ Wh,
                  uint4* __restrict__ ws) {
    int tid = blockIdx.x * blockDim.x + threadIdx.x;  // 0 .. 229375
    const float* src; uint4* dst; int C, idx;
    if (tid < 64 * 512)                  { src = Wq; dst = ws;          C = 512;  idx = tid; }
    else if (tid < 64 * 512 + 64 * 1536) { src = Wx; dst = ws + WX_OFF; C = 1536; idx = tid - 64 * 512; }
    else                                 { src = Wh; dst = ws + WH_OFF; C = 1536; idx = tid - (64 * 512 + 64 * 1536); }
    int m4 = idx / C;
    int c  = idx - m4 * C;
    const float* s = src + (size_t)(m4 * 8) * C + c;
    uint4 o;
    o.x = pack2f16(s[0 * (size_t)C], s[1 * (size_t)C]);
    o.y = pack2f16(s[2 * (size_t)C], s[3 * (size_t)C]);
    o.z = pack2f16(s[4 * (size_t)C], s[5 * (size_t)C]);
    o.w = pack2f16(s[6 * (size_t)C], s[7 * (size_t)C]);
    dst[idx] = o;
}

// 256 blocks. gid = blk & 7 (XCD-local group, heuristic), bid = blk >> 3.
// Group gid owns batches 8*gid..8*gid+7; block bid owns cols [bid*16, bid*16+16).
__global__ __launch_bounds__(THREADS)
void gru_scan(const int* __restrict__ xtok, const float* __restrict__ emb,
              const uint4* __restrict__ wsp, const float* __restrict__ bx,
              const float* __restrict__ bh, const float* __restrict__ W1,
              const float* __restrict__ b1, const float* __restrict__ W2,
              const float* __restrict__ b2, float* __restrict__ out)
{
    const int blk  = blockIdx.x;
    const int gid  = blk & 7;
    const int bid  = blk >> 3;
    const int tid  = threadIdx.x;
    const int lane = tid & 63;
    const int wid  = tid >> 6;
    const int colsub = lane & 7;
    const int bp     = (lane >> 3) & 3;
    const int chsub  = lane >> 5;

    char* sync = (char*)wsp + SYNC_OFF;
    unsigned int* flagS = (unsigned int*)sync;
    unsigned int* flagH = (unsigned int*)(sync + 1024);
    unsigned int* Hbuf  = (unsigned int*)(sync + 2048);
    float* Pbuf         = (float*)(sync + 133120);
    float* pooled_g     = (float*)(sync + 182272);
    float* fc1_g        = (float*)(sync + 313344);

    __shared__ uint4 lds_W [64][65];   // cols 0..15 Wq-slice, 16..63 Wh-slice (r,z,n x16)
    __shared__ uint4 lds_Wx[64][49];   // 48 Wx cols (r,z,n x16)
    __shared__ uint4 lds_h [8][66];
    __shared__ uint4 lds_ctx[8][66];
    __shared__ float red[8][64][9];
    __shared__ float sum[64][9];
    __shared__ float a_lds[8][8][3];

    // ---- persistent weight slices -> LDS ----
    for (int i = tid; i < 64 * 64; i += THREADS) {
        int ch = i >> 6, cl = i & 63;
        uint4 v;
        if (cl < 16) v = wsp[WQ_OFF + ch * 512 + bid * 16 + cl];
        else { int g = (cl - 16) >> 4, c = (cl - 16) & 15;
               v = wsp[WH_OFF + ch * 1536 + g * 512 + bid * 16 + c]; }
        lds_W[ch][cl] = v;
    }
    for (int i = tid; i < 64 * 48; i += THREADS) {
        int ch = i / 48, cl = i - ch * 48;
        int g = cl >> 4, c = cl & 15;
        lds_Wx[ch][cl] = wsp[WX_OFF + ch * 1536 + g * 512 + bid * 16 + c];
    }

    float bxr = 0, bxz = 0, bxn = 0, bhr = 0, bhz = 0, bhn = 0;
    if (tid < 128) {
        int c = tid >> 3;
        int cg = bid * 16 + c;
        bxr = bx[cg]; bxz = bx[512 + cg]; bxn = bx[1024 + cg];
        bhr = bh[cg]; bhz = bh[512 + cg]; bhn = bh[1024 + cg];
    }
    float hprev = 0.f, pooledv = 0.f;
    __syncthreads();

    for (int t = 0; t < SEQ; ++t) {
        const int par = t & 1;

        // ======== prefetch (independent of h(t-1)) ========
        const int b  = wid;               // ctx batch for this wave
        const int gb = gid * 8 + b;
        int tk0 = (t >= 2) ? xtok[gb * SEQ + t - 2] : -1;
        int tk1 = (t >= 1) ? xtok[gb * SEQ + t - 1] : -1;
        int tk2 = xtok[gb * SEQ + t];
        float4 e0a = {0,0,0,0}, e0b = {0,0,0,0};
        float4 e1a = {0,0,0,0}, e1b = {0,0,0,0};
        float4 e2a, e2b;
        if (tk0 >= 0) { const float4* p = (const float4*)(emb + (size_t)tk0 * 512 + lane * 8); e0a = p[0]; e0b = p[1]; }
        if (tk1 >= 0) { const float4* p = (const float4*)(emb + (size_t)tk1 * 512 + lane * 8); e1a = p[0]; e1b = p[1]; }
        { const float4* p = (const float4*)(emb + (size_t)tk2 * 512 + lane * 8); e2a = p[0]; e2b = p[1]; }

        float winv[16];
        int b3 = 0, g3 = 0, trow = -1;
        if (wid == 0 && lane < 24) {
            b3 = lane / 3; g3 = lane - b3 * 3;
            trow = t - 2 + g3;
            int tok = (trow >= 0) ? xtok[(gid * 8 + b3) * SEQ + trow] : -1;
            if (tok >= 0) {
                const float* er = emb + (size_t)tok * 512 + bid * 16;
                #pragma unroll
                for (int d = 0; d < 16; ++d) winv[d] = er[d];
            } else {
                #pragma unroll
                for (int d = 0; d < 16; ++d) winv[d] = 0.f;
            }
        }

        // ======== wait: h(t-1) published by all 32 blocks of group ========
        if (wid == 0) {
            bool done = lane >= 32;
            while (!__all(done)) {
                if (!done) done = (__hip_atomic_load(&flagH[gid * 32 + lane],
                                   __ATOMIC_RELAXED, __HIP_MEMORY_SCOPE_AGENT) >= (unsigned)t);
                if (!__all(done)) __builtin_amdgcn_s_sleep(2);
            }
            __threadfence();
        }
        __syncthreads();

        // ======== load full h(t-1) -> LDS ========
        {
            const uint4* hsrc = (const uint4*)(Hbuf + (size_t)(par ^ 1) * 16384);
            for (int i = tid; i < 8 * 64; i += THREADS) {
                int bb = i >> 6, ch = i & 63;
                lds_h[bb][ch] = hsrc[(gid * 8 + bb) * 64 + ch];
            }
        }
        __syncthreads();

        // ======== GEMM-q (cols 0..15) ========
        {
            float aq0 = 0, aq1 = 0, aq2 = 0, aq3 = 0;
            int ch0 = wid * 8 + chsub * 4;
            #pragma unroll
            for (int i = 0; i < 4; ++i) {
                int ch = ch0 + i;
                uint4 h0 = lds_h[bp][ch], h1 = lds_h[bp + 4][ch];
                uint4 w0 = lds_W[ch][colsub], w1 = lds_W[ch][colsub + 8];
                aq0 = dot4(h0, w0, aq0); aq1 = dot4(h0, w1, aq1);
                aq2 = dot4(h1, w0, aq2); aq3 = dot4(h1, w1, aq3);
            }
            aq0 += __shfl_xor(aq0, 32); aq1 += __shfl_xor(aq1, 32);
            aq2 += __shfl_xor(aq2, 32); aq3 += __shfl_xor(aq3, 32);
            if (chsub == 0) {
                red[wid][colsub][bp]       = aq0; red[wid][colsub + 8][bp]     = aq1;
                red[wid][colsub][bp + 4]   = aq2; red[wid][colsub + 8][bp + 4] = aq3;
            }
        }
        __syncthreads();

        // ======== wave0: partial scores + EARLY publish ========
        if (wid == 0 && lane < 24) {
            float s = 0.f;
            if (trow >= 0) {
                #pragma unroll
                for (int d = 0; d < 16; ++d) {
                    float q = red[0][d][b3];
                    #pragma unroll
                    for (int k = 1; k < 8; ++k) q += red[k][d][b3];
                    s += winv[d] * q;
                }
            }
            Pbuf[(size_t)((par * 8 + gid) * 32 + bid) * 24 + b3 * 3 + g3] = s;
        }
        if (wid == 0) {
            __threadfence();
            if (lane == 0)
                __hip_atomic_store(&flagS[gid * 32 + bid], (unsigned)(t + 1),
                                   __ATOMIC_RELEASE, __HIP_MEMORY_SCOPE_AGENT);
        }

        // ======== GEMM-gh (cols 16..63), overlaps others' score publishes ========
        {
            float ag[12];
            #pragma unroll
            for (int i = 0; i < 12; ++i) ag[i] = 0.f;
            int ch0 = wid * 8 + chsub * 4;
            #pragma unroll
            for (int i = 0; i < 4; ++i) {
                int ch = ch0 + i;
                uint4 h0 = lds_h[bp][ch], h1 = lds_h[bp + 4][ch];
                #pragma unroll
                for (int j = 0; j < 6; ++j) {
                    uint4 w = lds_W[ch][16 + colsub + 8 * j];
                    ag[j]     = dot4(h0, w, ag[j]);
                    ag[6 + j] = dot4(h1, w, ag[6 + j]);
                }
            }
            #pragma unroll
            for (int i = 0; i < 12; ++i) ag[i] += __shfl_xor(ag[i], 32);
            if (chsub == 0) {
                #pragma unroll
                for (int j = 0; j < 6; ++j) {
                    red[wid][16 + colsub + 8 * j][bp]     = ag[j];
                    red[wid][16 + colsub + 8 * j][bp + 4] = ag[6 + j];
                }
            }
        }
        __syncthreads();

        // ======== gh-sum (waves 1-6) | wave0: wait scores ========
        if (tid >= 64 && tid < 448) {
            int idx = tid - 64;
            int col = 16 + (idx >> 3), bb = idx & 7;
            float s = red[0][col][bb];
            #pragma unroll
            for (int k = 1; k < 8; ++k) s += red[k][col][bb];
            sum[col][bb] = s;
        }
        if (wid == 0) {
            bool done = lane >= 32;
            while (!__all(done)) {
                if (!done) done = (__hip_atomic_load(&flagS[gid * 32 + lane],
                                   __ATOMIC_RELAXED, __HIP_MEMORY_SCOPE_AGENT) >= (unsigned)(t + 1));
                if (!__all(done)) __builtin_amdgcn_s_sleep(2);
            }
            __threadfence();
        }
        __syncthreads();

        // ======== softmax (redundant per block, tiny) ========
        if (tid < 64) {
            int bb = tid >> 3, n = tid & 7;
            const float* pb = Pbuf + (size_t)(par * 8 + gid) * 32 * 24;
            float sc0 = 0, sc1 = 0, sc2 = 0;
            #pragma unroll
            for (int j = 0; j < 4; ++j) {
                const float* pj = pb + (n * 4 + j) * 24 + bb * 3;
                sc0 += pj[0]; sc1 += pj[1]; sc2 += pj[2];
            }
            sc0 *= 0.125f; sc1 *= 0.125f; sc2 *= 0.125f;
            float mx = fmaxf(sc0, fmaxf(sc1, sc2));
            float e0 = __expf(sc0 - mx), e1 = __expf(sc1 - mx), e2 = __expf(sc2 - mx);
            float inv = 1.f / (e0 + e1 + e2);
            a_lds[bb][n][0] = e0 * inv; a_lds[bb][n][1] = e1 * inv; a_lds[bb][n][2] = e2 * inv;
        }
        __syncthreads();

        // ======== ctx build from prefetched regs ========
        {
            int head = lane >> 3;
            float a0 = a_lds[b][head][0], a1 = a_lds[b][head][1], a2 = a_lds[b][head][2];
            float c0 = a0 * e0a.x + a1 * e1a.x + a2 * e2a.x;
            float c1 = a0 * e0a.y + a1 * e1a.y + a2 * e2a.y;
            float c2 = a0 * e0a.z + a1 * e1a.z + a2 * e2a.z;
            float c3 = a0 * e0a.w + a1 * e1a.w + a2 * e2a.w;
            float c4 = a0 * e0b.x + a1 * e1b.x + a2 * e2b.x;
            float c5 = a0 * e0b.y + a1 * e1b.y + a2 * e2b.y;
            float c6 = a0 * e0b.z + a1 * e1b.z + a2 * e2b.z;
            float c7 = a0 * e0b.w + a1 * e1b.w + a2 * e2b.w;
            uint4 pk;
            pk.x = pack2f16(c0, c1); pk.y = pack2f16(c2, c3);
            pk.z = pack2f16(c4, c5); pk.w = pack2f16(c6, c7);
            lds_ctx[b][lane] = pk;
        }
        __syncthreads();

        // ======== GEMM2: gx (48 cols) ========
        {
            float acx[12];
            #pragma unroll
            for (int i = 0; i < 12; ++i) acx[i] = 0.f;
            int ch0 = wid * 8 + chsub * 4;
            #pragma unroll
            for (int i = 0; i < 4; ++i) {
                int ch = ch0 + i;
                uint4 c0 = lds_ctx[bp][ch];
                uint4 c1 = lds_ctx[bp + 4][ch];
                #pragma unroll
                for (int j = 0; j < 6; ++j) {
                    uint4 w = lds_Wx[ch][colsub + 8 * j];
                    acx[j]     = dot4(c0, w, acx[j]);
                    acx[6 + j] = dot4(c1, w, acx[6 + j]);
                }
            }
            #pragma unroll
            for (int i = 0; i < 12; ++i) acx[i] += __shfl_xor(acx[i], 32);
            if (chsub == 0) {
                #pragma unroll
                for (int j = 0; j < 6; ++j) {
                    red[wid][colsub + 8 * j][bp]     = acx[j];
                    red[wid][colsub + 8 * j][bp + 4] = acx[6 + j];
                }
            }
        }
        __syncthreads();

        // ======== GRU pointwise + h publish ========
        if (tid < 128) {
            int c = tid >> 3, bb = tid & 7;
            float gxr = bxr, gxz = bxz, gxn = bxn;
            #pragma unroll
            for (int k = 0; k < 8; ++k) {
                gxr += red[k][c][bb];
                gxz += red[k][16 + c][bb];
                gxn += red[k][32 + c][bb];
            }
            float ghr = sum[16 + c][bb] + bhr;
            float ghz = sum[32 + c][bb] + bhz;
            float ghn = sum[48 + c][bb] + bhn;
            float r = fsigmoid(gxr + ghr);
            float z = fsigmoid(gxz + ghz);
            float n = ftanhf(gxn + r * ghn);
            float hnew = (1.f - z) * n + z * hprev;
            hprev = hnew; pooledv += hnew;
            float hnext = __shfl_down(hnew, 8);
            if ((c & 1) == 0)
                Hbuf[(size_t)par * 16384 + (gid * 8 + bb) * 256 + bid * 8 + (c >> 1)]
                    = pack2f16(hnew, hnext);
        }
        __threadfence();
        __syncthreads();
        if (tid == 0)
            __hip_atomic_store(&flagH[gid * 32 + bid], (unsigned)(t + 1),
                               __ATOMIC_RELEASE, __HIP_MEMORY_SCOPE_AGENT);
    }

    // ======== epilogue: pooled -> relu -> FC1 -> FC2 ========
    if (tid < 128) {
        int c = tid >> 3, bb = tid & 7;
        pooled_g[(gid * 8 + bb) * 512 + bid * 16 + c] = fmaxf(pooledv, 0.f);
    }
    __threadfence();
    __syncthreads();
    if (tid == 0)
        __hip_atomic_store(&flagS[gid * 32 + bid], (unsigned)(SEQ + 1),
                           __ATOMIC_RELEASE, __HIP_MEMORY_SCOPE_AGENT);
    if (wid == 0) {
        bool done = lane >= 32;
        while (!__all(done)) {
            if (!done) done = (__hip_atomic_load(&flagS[gid * 32 + lane],
                               __ATOMIC_RELAXED, __HIP_MEMORY_SCOPE_AGENT) >= (unsigned)(SEQ + 1));
            if (!__all(done)) __builtin_amdgcn_s_sleep(2);
        }
        __threadfence();
    }
    __syncthreads();

    if (tid < 128) {
        int c = tid >> 3, bb = tid & 7;
        int cg = bid * 16 + c;
        const float* pr = pooled_g + (size_t)(gid * 8 + bb) * 512;
        float acc1 = b1[cg];
        for (int k = 0; k < 512; ++k) acc1 += pr[k] * W1[(size_t)k * 512 + cg];
        fc1_g[(gid * 8 + bb) * 512 + cg] = acc1;
    }
    __threadfence();
    __syncthreads();
    if (tid == 0)
        __hip_atomic_store(&flagH[gid * 32 + bid], (unsigned)(SEQ + 1),
                           __ATOMIC_RELEASE, __HIP_MEMORY_SCOPE_AGENT);

    if (bid == 0) {
        if (wid == 0) {
            bool done = lane >= 32;
            while (!__all(done)) {
                if (!done) done = (__hip_atomic_load(&flagH[gid * 32 + lane],
                                   __ATOMIC_RELAXED, __HIP_MEMORY_SCOPE_AGENT) >= (unsigned)(SEQ + 1));
                if (!__all(done)) __builtin_amdgcn_s_sleep(2);
            }
            __threadfence();
        }
        __syncthreads();
        if (tid < 80) {
            int bb = tid / 10, cls = tid - bb * 10;
            const float* fr = fc1_g + (size_t)(gid * 8 + bb) * 512;
            float a2 = b2[cls];
            for (int k = 0; k < 512; ++k) a2 += fr[k] * W2[k * 10 + cls];
            out[(gid * 8 + bb) * 10 + cls] = a2;
        }
    }
}

extern "C" void kernel_launch(void* const* d_in, const int* in_sizes, int n_in,
                              void* d_out, int out_size, void* d_ws, size_t ws_size,
                              hipStream_t stream) {
    const int*   x   = (const int*)d_in[0];
    const float* emb = (const float*)d_in[1];
    const float* Wq  = (const float*)d_in[2];
    const float* Wx  = (const float*)d_in[3];
    const float* Wh  = (const float*)d_in[4];
    const float* bx  = (const float*)d_in[5];
    const float* bh  = (const float*)d_in[6];
    const float* W1  = (const float*)d_in[7];
    const float* b1  = (const float*)d_in[8];
    const float* W2  = (const float*)d_in[9];
    const float* b2  = (const float*)d_in[10];
    uint4* wsp = (uint4*)d_ws;
    float* outp = (float*)d_out;

    hipLaunchKernelGGL(pack_weights, dim3(896), dim3(256), 0, stream, Wq, Wx, Wh, wsp);
    hipMemsetAsync((char*)d_ws + SYNC_OFF, 0, 133120, stream);

    void* args[] = { (void*)&x, (void*)&emb, (void*)&wsp, (void*)&bx, (void*)&bh,
                     (void*)&W1, (void*)&b1, (void*)&W2, (void*)&b2, (void*)&outp };
    hipError_t e = hipLaunchCooperativeKernel((void*)gru_scan, dim3(256), dim3(THREADS),
                                              args, 0, stream);
    if (e != hipSuccess) {
        hipLaunchKernelGGL(gru_scan, dim3(256), dim3(THREADS), 0, stream,
                           x, emb, wsp, bx, bh, W1, b1, W2, b2, outp);
    }
}

// Round 5
// 4267.875 us; speedup vs baseline: 9.7620x; 6.6665x over previous
//
#include <hip/hip_runtime.h>
#include <hip/hip_fp16.h>

typedef __attribute__((ext_vector_type(2))) _Float16 half2v;
typedef __attribute__((ext_vector_type(2))) __fp16   fp16x2;

#define SEQ     512
#define THREADS 512

// ws layout (uint4 units for weights):
#define WQ_OFF   0
#define WX_OFF   (64*512)
#define WH_OFF   (64*512 + 64*1536)
#define SYNC_OFF 3670016   // bytes: end of packed weights (229376*16)
// sync region (bytes): flagS u32[256]@0 ; flagH u32[256]@1024 ;
// Hbuf u32[2][8g][8b][256]@2048 (131072) ; Pbuf f32[2][8][32][24]@133120 ;
// pooled f32[64][512]@182272 ; fc1 f32[64][512]@313344

__device__ inline unsigned int pack2f16(float a, float b) {
    fp16x2 p = __builtin_amdgcn_cvt_pkrtz(a, b);
    return __builtin_bit_cast(unsigned int, p);
}
__device__ inline float fdot2u(unsigned int a, unsigned int b, float acc) {
    return __builtin_amdgcn_fdot2(__builtin_bit_cast(half2v, a),
                                  __builtin_bit_cast(half2v, b), acc, false);
}
__device__ inline float dot4(uint4 h, uint4 w, float acc) {
    acc = fdot2u(h.x, w.x, acc); acc = fdot2u(h.y, w.y, acc);
    acc = fdot2u(h.z, w.z, acc); acc = fdot2u(h.w, w.w, acc);
    return acc;
}
__device__ inline float fsigmoid(float x) { return 1.f / (1.f + __expf(-x)); }
__device__ inline float ftanhf(float x) {
    float e = __expf(-2.f * fabsf(x));
    float t = (1.f - e) / (1.f + e);
    return copysignf(t, x);
}

// fence-free sync primitives: relaxed agent-scope atomics (sc1, resolve at L3;
// no buffer_wbl2 / buffer_inv). Producer orders data-before-flag with vmcnt(0).
__device__ inline void vmem_fence() { asm volatile("s_waitcnt vmcnt(0)" ::: "memory"); }
__device__ inline unsigned a_ld(unsigned* p) {
    return __hip_atomic_load(p, __ATOMIC_RELAXED, __HIP_MEMORY_SCOPE_AGENT);
}
__device__ inline void a_st(unsigned* p, unsigned v) {
    __hip_atomic_store(p, v, __ATOMIC_RELAXED, __HIP_MEMORY_SCOPE_AGENT);
}
__device__ inline float a_ldf(float* p) {
    return __hip_atomic_load(p, __ATOMIC_RELAXED, __HIP_MEMORY_SCOPE_AGENT);
}
__device__ inline void a_stf(float* p, float v) {
    __hip_atomic_store(p, v, __ATOMIC_RELAXED, __HIP_MEMORY_SCOPE_AGENT);
}

__global__ __launch_bounds__(256)
void pack_weights(const float* __restrict__ Wq,
                  const float* __restrict__ Wx,
                  const float* __restrict__ Wh,
                  uint4* __restrict__ ws) {
    int tid = blockIdx.x * blockDim.x + threadIdx.x;  // 0 .. 229375
    const float* src; uint4* dst; int C, idx;
    if (tid < 64 * 512)                  { src = Wq; dst = ws;          C = 512;  idx = tid; }
    else if (tid < 64 * 512 + 64 * 1536) { src = Wx; dst = ws + WX_OFF; C = 1536; idx = tid - 64 * 512; }
    else                                 { src = Wh; dst = ws + WH_OFF; C = 1536; idx = tid - (64 * 512 + 64 * 1536); }
    int m4 = idx / C;
    int c  = idx - m4 * C;
    const float* s = src + (size_t)(m4 * 8) * C + c;
    uint4 o;
    o.x = pack2f16(s[0 * (size_t)C], s[1 * (size_t)C]);
    o.y = pack2f16(s[2 * (size_t)C], s[3 * (size_t)C]);
    o.z = pack2f16(s[4 * (size_t)C], s[5 * (size_t)C]);
    o.w = pack2f16(s[6 * (size_t)C], s[7 * (size_t)C]);
    dst[idx] = o;
}

// 256 blocks. gid = blk & 7 (XCD-local group heuristic), bid = blk >> 3.
// Group gid owns batches 8*gid..8*gid+7; block bid owns cols [bid*16, bid*16+16).
__global__ __launch_bounds__(THREADS)
void gru_scan(const int* __restrict__ xtok, const float* __restrict__ emb,
              const uint4* __restrict__ wsp, const float* __restrict__ bx,
              const float* __restrict__ bh, const float* __restrict__ W1,
              const float* __restrict__ b1, const float* __restrict__ W2,
              const float* __restrict__ b2, float* __restrict__ out)
{
    const int blk  = blockIdx.x;
    const int gid  = blk & 7;
    const int bid  = blk >> 3;
    const int tid  = threadIdx.x;
    const int lane = tid & 63;
    const int wid  = tid >> 6;
    const int colsub = lane & 7;
    const int bp     = (lane >> 3) & 3;
    const int chsub  = lane >> 5;

    char* sync = (char*)wsp + SYNC_OFF;
    unsigned int* flagS = (unsigned int*)sync;
    unsigned int* flagH = (unsigned int*)(sync + 1024);
    unsigned int* Hbuf  = (unsigned int*)(sync + 2048);
    float* Pbuf         = (float*)(sync + 133120);
    float* pooled_g     = (float*)(sync + 182272);
    float* fc1_g        = (float*)(sync + 313344);

    __shared__ uint4 lds_W [64][65];   // cols 0..15 Wq-slice, 16..63 Wh-slice (r,z,n x16)
    __shared__ uint4 lds_Wx[64][49];   // 48 Wx cols (r,z,n x16)
    __shared__ uint4 lds_h [8][66];
    __shared__ uint4 lds_ctx[8][66];
    __shared__ float red[8][64][9];    // also reused as [8][512] staging in epilogue
    __shared__ float sum[64][9];
    __shared__ float a_lds[8][8][3];

    // ---- persistent weight slices -> LDS ----
    for (int i = tid; i < 64 * 64; i += THREADS) {
        int ch = i >> 6, cl = i & 63;
        uint4 v;
        if (cl < 16) v = wsp[WQ_OFF + ch * 512 + bid * 16 + cl];
        else { int g = (cl - 16) >> 4, c = (cl - 16) & 15;
               v = wsp[WH_OFF + ch * 1536 + g * 512 + bid * 16 + c]; }
        lds_W[ch][cl] = v;
    }
    for (int i = tid; i < 64 * 48; i += THREADS) {
        int ch = i / 48, cl = i - ch * 48;
        int g = cl >> 4, c = cl & 15;
        lds_Wx[ch][cl] = wsp[WX_OFF + ch * 1536 + g * 512 + bid * 16 + c];
    }

    float bxr = 0, bxz = 0, bxn = 0, bhr = 0, bhz = 0, bhn = 0;
    if (tid < 128) {
        int c = tid >> 3;
        int cg = bid * 16 + c;
        bxr = bx[cg]; bxz = bx[512 + cg]; bxn = bx[1024 + cg];
        bhr = bh[cg]; bhz = bh[512 + cg]; bhn = bh[1024 + cg];
    }
    float hprev = 0.f, pooledv = 0.f;
    __syncthreads();

    for (int t = 0; t < SEQ; ++t) {
        const int par = t & 1;

        // ======== prefetch (independent of h(t-1)) ========
        const int b  = wid;               // ctx batch for this wave
        const int gb = gid * 8 + b;
        int tk0 = (t >= 2) ? xtok[gb * SEQ + t - 2] : -1;
        int tk1 = (t >= 1) ? xtok[gb * SEQ + t - 1] : -1;
        int tk2 = xtok[gb * SEQ + t];
        float4 e0a = {0,0,0,0}, e0b = {0,0,0,0};
        float4 e1a = {0,0,0,0}, e1b = {0,0,0,0};
        float4 e2a, e2b;
        if (tk0 >= 0) { const float4* p = (const float4*)(emb + (size_t)tk0 * 512 + lane * 8); e0a = p[0]; e0b = p[1]; }
        if (tk1 >= 0) { const float4* p = (const float4*)(emb + (size_t)tk1 * 512 + lane * 8); e1a = p[0]; e1b = p[1]; }
        { const float4* p = (const float4*)(emb + (size_t)tk2 * 512 + lane * 8); e2a = p[0]; e2b = p[1]; }

        float winv[16];
        int b3 = 0, g3 = 0, trow = -1;
        if (wid == 0 && lane < 24) {
            b3 = lane / 3; g3 = lane - b3 * 3;
            trow = t - 2 + g3;
            int tok = (trow >= 0) ? xtok[(gid * 8 + b3) * SEQ + trow] : -1;
            if (tok >= 0) {
                const float* er = emb + (size_t)tok * 512 + bid * 16;
                #pragma unroll
                for (int d = 0; d < 16; ++d) winv[d] = er[d];
            } else {
                #pragma unroll
                for (int d = 0; d < 16; ++d) winv[d] = 0.f;
            }
        }

        // ======== wait: h(t-1) published by all 32 blocks of group ========
        if (wid == 0) {
            bool done = lane >= 32;
            while (!__all(done)) {
                if (!done) done = (a_ld(&flagH[gid * 32 + lane]) >= (unsigned)t);
                if (!__all(done)) __builtin_amdgcn_s_sleep(1);
            }
        }
        __syncthreads();

        // ======== load full h(t-1) -> LDS (relaxed atomic loads, L3-fresh) ========
        {
            unsigned* hsrc = Hbuf + (size_t)(par ^ 1) * 16384;
            for (int i = tid; i < 8 * 64; i += THREADS) {
                int bb = i >> 6, ch = i & 63;
                unsigned* s = hsrc + (gid * 8 + bb) * 256 + ch * 4;
                uint4 v;
                v.x = a_ld(s); v.y = a_ld(s + 1); v.z = a_ld(s + 2); v.w = a_ld(s + 3);
                lds_h[bb][ch] = v;
            }
        }
        __syncthreads();

        // ======== GEMM-q (cols 0..15) ========
        {
            float aq0 = 0, aq1 = 0, aq2 = 0, aq3 = 0;
            int ch0 = wid * 8 + chsub * 4;
            #pragma unroll
            for (int i = 0; i < 4; ++i) {
                int ch = ch0 + i;
                uint4 h0 = lds_h[bp][ch], h1 = lds_h[bp + 4][ch];
                uint4 w0 = lds_W[ch][colsub], w1 = lds_W[ch][colsub + 8];
                aq0 = dot4(h0, w0, aq0); aq1 = dot4(h0, w1, aq1);
                aq2 = dot4(h1, w0, aq2); aq3 = dot4(h1, w1, aq3);
            }
            aq0 += __shfl_xor(aq0, 32); aq1 += __shfl_xor(aq1, 32);
            aq2 += __shfl_xor(aq2, 32); aq3 += __shfl_xor(aq3, 32);
            if (chsub == 0) {
                red[wid][colsub][bp]       = aq0; red[wid][colsub + 8][bp]     = aq1;
                red[wid][colsub][bp + 4]   = aq2; red[wid][colsub + 8][bp + 4] = aq3;
            }
        }
        __syncthreads();

        // ======== wave0: partial scores + EARLY publish (data then vmcnt then flag) ========
        if (wid == 0 && lane < 24) {
            float s = 0.f;
            if (trow >= 0) {
                #pragma unroll
                for (int d = 0; d < 16; ++d) {
                    float q = red[0][d][b3];
                    #pragma unroll
                    for (int k = 1; k < 8; ++k) q += red[k][d][b3];
                    s += winv[d] * q;
                }
            }
            a_stf(&Pbuf[(size_t)((par * 8 + gid) * 32 + bid) * 24 + b3 * 3 + g3], s);
        }
        if (wid == 0) {
            vmem_fence();
            if (lane == 0) a_st(&flagS[gid * 32 + bid], (unsigned)(t + 1));
        }

        // ======== GEMM-gh (cols 16..63), overlaps others' score publishes ========
        {
            float ag[12];
            #pragma unroll
            for (int i = 0; i < 12; ++i) ag[i] = 0.f;
            int ch0 = wid * 8 + chsub * 4;
            #pragma unroll
            for (int i = 0; i < 4; ++i) {
                int ch = ch0 + i;
                uint4 h0 = lds_h[bp][ch], h1 = lds_h[bp + 4][ch];
                #pragma unroll
                for (int j = 0; j < 6; ++j) {
                    uint4 w = lds_W[ch][16 + colsub + 8 * j];
                    ag[j]     = dot4(h0, w, ag[j]);
                    ag[6 + j] = dot4(h1, w, ag[6 + j]);
                }
            }
            #pragma unroll
            for (int i = 0; i < 12; ++i) ag[i] += __shfl_xor(ag[i], 32);
            if (chsub == 0) {
                #pragma unroll
                for (int j = 0; j < 6; ++j) {
                    red[wid][16 + colsub + 8 * j][bp]     = ag[j];
                    red[wid][16 + colsub + 8 * j][bp + 4] = ag[6 + j];
                }
            }
        }
        __syncthreads();

        // ======== gh-sum (waves 1-6) | wave0: wait scores ========
        if (tid >= 64 && tid < 448) {
            int idx = tid - 64;
            int col = 16 + (idx >> 3), bb = idx & 7;
            float s = red[0][col][bb];
            #pragma unroll
            for (int k = 1; k < 8; ++k) s += red[k][col][bb];
            sum[col][bb] = s;
        }
        if (wid == 0) {
            bool done = lane >= 32;
            while (!__all(done)) {
                if (!done) done = (a_ld(&flagS[gid * 32 + lane]) >= (unsigned)(t + 1));
                if (!__all(done)) __builtin_amdgcn_s_sleep(1);
            }
        }
        __syncthreads();

        // ======== softmax (redundant per block, tiny; atomic reads of Pbuf) ========
        if (tid < 64) {
            int bb = tid >> 3, n = tid & 7;
            float* pb = Pbuf + (size_t)(par * 8 + gid) * 32 * 24;
            float sc0 = 0, sc1 = 0, sc2 = 0;
            #pragma unroll
            for (int j = 0; j < 4; ++j) {
                float* pj = pb + (n * 4 + j) * 24 + bb * 3;
                sc0 += a_ldf(pj); sc1 += a_ldf(pj + 1); sc2 += a_ldf(pj + 2);
            }
            sc0 *= 0.125f; sc1 *= 0.125f; sc2 *= 0.125f;
            float mx = fmaxf(sc0, fmaxf(sc1, sc2));
            float e0 = __expf(sc0 - mx), e1 = __expf(sc1 - mx), e2 = __expf(sc2 - mx);
            float inv = 1.f / (e0 + e1 + e2);
            a_lds[bb][n][0] = e0 * inv; a_lds[bb][n][1] = e1 * inv; a_lds[bb][n][2] = e2 * inv;
        }
        __syncthreads();

        // ======== ctx build from prefetched regs ========
        {
            int head = lane >> 3;
            float a0 = a_lds[b][head][0], a1 = a_lds[b][head][1], a2 = a_lds[b][head][2];
            float c0 = a0 * e0a.x + a1 * e1a.x + a2 * e2a.x;
            float c1 = a0 * e0a.y + a1 * e1a.y + a2 * e2a.y;
            float c2 = a0 * e0a.z + a1 * e1a.z + a2 * e2a.z;
            float c3 = a0 * e0a.w + a1 * e1a.w + a2 * e2a.w;
            float c4 = a0 * e0b.x + a1 * e1b.x + a2 * e2b.x;
            float c5 = a0 * e0b.y + a1 * e1b.y + a2 * e2b.y;
            float c6 = a0 * e0b.z + a1 * e1b.z + a2 * e2b.z;
            float c7 = a0 * e0b.w + a1 * e1b.w + a2 * e2b.w;
            uint4 pk;
            pk.x = pack2f16(c0, c1); pk.y = pack2f16(c2, c3);
            pk.z = pack2f16(c4, c5); pk.w = pack2f16(c6, c7);
            lds_ctx[b][lane] = pk;
        }
        __syncthreads();

        // ======== GEMM2: gx (48 cols) ========
        {
            float acx[12];
            #pragma unroll
            for (int i = 0; i < 12; ++i) acx[i] = 0.f;
            int ch0 = wid * 8 + chsub * 4;
            #pragma unroll
            for (int i = 0; i < 4; ++i) {
                int ch = ch0 + i;
                uint4 c0 = lds_ctx[bp][ch];
                uint4 c1 = lds_ctx[bp + 4][ch];
                #pragma unroll
                for (int j = 0; j < 6; ++j) {
                    uint4 w = lds_Wx[ch][colsub + 8 * j];
                    acx[j]     = dot4(c0, w, acx[j]);
                    acx[6 + j] = dot4(c1, w, acx[6 + j]);
                }
            }
            #pragma unroll
            for (int i = 0; i < 12; ++i) acx[i] += __shfl_xor(acx[i], 32);
            if (chsub == 0) {
                #pragma unroll
                for (int j = 0; j < 6; ++j) {
                    red[wid][colsub + 8 * j][bp]     = acx[j];
                    red[wid][colsub + 8 * j][bp + 4] = acx[6 + j];
                }
            }
        }
        __syncthreads();

        // ======== GRU pointwise + h publish ========
        if (tid < 128) {
            int c = tid >> 3, bb = tid & 7;
            float gxr = bxr, gxz = bxz, gxn = bxn;
            #pragma unroll
            for (int k = 0; k < 8; ++k) {
                gxr += red[k][c][bb];
                gxz += red[k][16 + c][bb];
                gxn += red[k][32 + c][bb];
            }
            float ghr = sum[16 + c][bb] + bhr;
            float ghz = sum[32 + c][bb] + bhz;
            float ghn = sum[48 + c][bb] + bhn;
            float r = fsigmoid(gxr + ghr);
            float z = fsigmoid(gxz + ghz);
            float n = ftanhf(gxn + r * ghn);
            float hnew = (1.f - z) * n + z * hprev;
            hprev = hnew; pooledv += hnew;
            float hnext = __shfl_down(hnew, 8);
            if ((c & 1) == 0)
                a_st(&Hbuf[(size_t)par * 16384 + (gid * 8 + bb) * 256 + bid * 8 + (c >> 1)],
                     pack2f16(hnew, hnext));
        }
        vmem_fence();
        __syncthreads();
        if (tid == 0)
            a_st(&flagH[gid * 32 + bid], (unsigned)(t + 1));
    }

    // ======== epilogue: pooled -> relu -> FC1 -> FC2 ========
    float* stage = &red[0][0][0];   // reuse red as [8][512] staging
    if (tid < 128) {
        int c = tid >> 3, bb = tid & 7;
        a_stf(&pooled_g[(gid * 8 + bb) * 512 + bid * 16 + c], fmaxf(pooledv, 0.f));
    }
    vmem_fence();
    __syncthreads();
    if (tid == 0)
        a_st(&flagS[gid * 32 + bid], (unsigned)(SEQ + 1));
    if (wid == 0) {
        bool done = lane >= 32;
        while (!__all(done)) {
            if (!done) done = (a_ld(&flagS[gid * 32 + lane]) >= (unsigned)(SEQ + 1));
            if (!__all(done)) __builtin_amdgcn_s_sleep(1);
        }
    }
    __syncthreads();

    // stage pooled rows for this group into LDS
    for (int i = tid; i < 8 * 512; i += THREADS) {
        int bb = i >> 9, k = i & 511;
        stage[bb * 512 + k] = a_ldf(&pooled_g[(gid * 8 + bb) * 512 + k]);
    }
    __syncthreads();

    if (tid < 128) {
        int c = tid >> 3, bb = tid & 7;
        int cg = bid * 16 + c;
        const float* pr = stage + bb * 512;
        float acc1 = b1[cg];
        for (int k = 0; k < 512; ++k) acc1 += pr[k] * W1[(size_t)k * 512 + cg];
        a_stf(&fc1_g[(gid * 8 + bb) * 512 + cg], acc1);
    }
    vmem_fence();
    __syncthreads();
    if (tid == 0)
        a_st(&flagH[gid * 32 + bid], (unsigned)(SEQ + 1));

    if (bid == 0) {
        if (wid == 0) {
            bool done = lane >= 32;
            while (!__all(done)) {
                if (!done) done = (a_ld(&flagH[gid * 32 + lane]) >= (unsigned)(SEQ + 1));
                if (!__all(done)) __builtin_amdgcn_s_sleep(1);
            }
        }
        __syncthreads();
        for (int i = tid; i < 8 * 512; i += THREADS) {
            int bb = i >> 9, k = i & 511;
            stage[bb * 512 + k] = a_ldf(&fc1_g[(gid * 8 + bb) * 512 + k]);
        }
        __syncthreads();
        if (tid < 80) {
            int bb = tid / 10, cls = tid - bb * 10;
            const float* fr = stage + bb * 512;
            float a2 = b2[cls];
            for (int k = 0; k < 512; ++k) a2 += fr[k] * W2[k * 10 + cls];
            out[(gid * 8 + bb) * 10 + cls] = a2;
        }
    }
}

extern "C" void kernel_launch(void* const* d_in, const int* in_sizes, int n_in,
                              void* d_out, int out_size, void* d_ws, size_t ws_size,
                              hipStream_t stream) {
    const int*   x   = (const int*)d_in[0];
    const float* emb = (const float*)d_in[1];
    const float* Wq  = (const float*)d_in[2];
    const float* Wx  = (const float*)d_in[3];
    const float* Wh  = (const float*)d_in[4];
    const float* bx  = (const float*)d_in[5];
    const float* bh  = (const float*)d_in[6];
    const float* W1  = (const float*)d_in[7];
    const float* b1  = (const float*)d_in[8];
    const float* W2  = (const float*)d_in[9];
    const float* b2  = (const float*)d_in[10];
    uint4* wsp = (uint4*)d_ws;
    float* outp = (float*)d_out;

    hipLaunchKernelGGL(pack_weights, dim3(896), dim3(256), 0, stream, Wq, Wx, Wh, wsp);
    hipMemsetAsync((char*)d_ws + SYNC_OFF, 0, 133120, stream);

    void* args[] = { (void*)&x, (void*)&emb, (void*)&wsp, (void*)&bx, (void*)&bh,
                     (void*)&W1, (void*)&b1, (void*)&W2, (void*)&b2, (void*)&outp };
    hipError_t e = hipLaunchCooperativeKernel((void*)gru_scan, dim3(256), dim3(THREADS),
                                              args, 0, stream);
    if (e != hipSuccess) {
        hipLaunchKernelGGL(gru_scan, dim3(256), dim3(THREADS), 0, stream,
                           x, emb, wsp, bx, bh, W1, b1, W2, b2, outp);
    }
}